// Round 1
// baseline (82.901 us; speedup 1.0000x reference)
//
#include <hip/hip_runtime.h>

#define DEG 32
#define NIDX 33   // DEG + self
#define F 256

__global__ __launch_bounds__(256) void aggregator_kernel(
    const int* __restrict__ nodes,
    const int* __restrict__ nbr,
    const float* __restrict__ feats,
    float* __restrict__ out,
    int B)
{
    const int b = blockIdx.x;
    const int t = threadIdx.x;  // 0..255 == feature column

    __shared__ int s_idx[NIDX];
    __shared__ int s_first[NIDX];

    if (t < DEG) s_idx[t] = nbr[(size_t)b * DEG + t];
    if (t == DEG) s_idx[DEG] = nodes[b];
    __syncthreads();

    if (t < NIDX) {
        const int v = s_idx[t];
        int f = 1;
        for (int j = 0; j < t; ++j) {
            if (s_idx[j] == v) { f = 0; break; }
        }
        s_first[t] = f;
    }
    __syncthreads();

    float acc = 0.0f;
    int cnt = 0;
    #pragma unroll 4
    for (int d = 0; d < NIDX; ++d) {
        if (s_first[d]) {
            acc += feats[(size_t)s_idx[d] * F + t];
            cnt++;
        }
    }
    out[(size_t)b * F + t] = acc / (float)cnt;
}

extern "C" void kernel_launch(void* const* d_in, const int* in_sizes, int n_in,
                              void* d_out, int out_size, void* d_ws, size_t ws_size,
                              hipStream_t stream)
{
    const int*   nodes = (const int*)d_in[0];
    const int*   nbr   = (const int*)d_in[1];
    const float* feats = (const float*)d_in[2];
    float*       out   = (float*)d_out;

    const int B = in_sizes[0];  // 10000

    aggregator_kernel<<<B, 256, 0, stream>>>(nodes, nbr, feats, out, B);
}

// Round 2
// 55.905 us; speedup vs baseline: 1.4829x; 1.4829x over previous
//
#include <hip/hip_runtime.h>

#define DEG 32
#define NIDX 33          // DEG + self
#define F 256
#define F4 (F / 4)       // 64 float4 per row == one wave
#define RPB 4            // rows (waves) per 256-thread block

__global__ __launch_bounds__(256) void aggregator_kernel(
    const int* __restrict__ nodes,
    const int* __restrict__ nbr,
    const float* __restrict__ feats,
    float* __restrict__ out,
    int B)
{
    const int tid  = threadIdx.x;
    const int wave = tid >> 6;    // 0..3  -> row within block
    const int lane = tid & 63;    // float4 column chunk
    const int b    = blockIdx.x * RPB + wave;

    __shared__ int   s_idx[RPB][NIDX];
    __shared__ float s_w[RPB][NIDX];

    // ---- stage indices: 4 rows x 33 entries, one thread each ----
    const int r = tid / NIDX;
    const int d = tid - r * NIDX;
    if (tid < RPB * NIDX) {
        const int bb = blockIdx.x * RPB + r;
        int v = 0;
        if (bb < B) v = (d < DEG) ? nbr[(size_t)bb * DEG + d] : nodes[bb];
        s_idx[r][d] = v;
    }
    __syncthreads();

    // ---- first-occurrence weights (quadratic scan, 33^2 trivial) ----
    if (tid < RPB * NIDX) {
        const int v = s_idx[r][d];
        float w = 1.0f;
        for (int j = 0; j < d; ++j) {
            if (s_idx[r][j] == v) { w = 0.0f; break; }
        }
        s_w[r][d] = w;
    }
    __syncthreads();

    if (b >= B) return;

    // ---- pull indices/weights into registers (broadcast LDS reads) ----
    int   base[NIDX];
    float w[NIDX];
    float den = 0.0f;
    #pragma unroll
    for (int k = 0; k < NIDX; ++k) {
        base[k] = s_idx[wave][k];
        w[k]    = s_w[wave][k];
        den    += w[k];
    }

    // ---- branch-free gather-accumulate: all 33 loads issue independently ----
    const float4* __restrict__ f4 = (const float4*)feats;
    float4 acc = make_float4(0.f, 0.f, 0.f, 0.f);
    #pragma unroll
    for (int k = 0; k < NIDX; ++k) {
        const float4 v = f4[(size_t)base[k] * F4 + lane];
        acc.x = fmaf(w[k], v.x, acc.x);
        acc.y = fmaf(w[k], v.y, acc.y);
        acc.z = fmaf(w[k], v.z, acc.z);
        acc.w = fmaf(w[k], v.w, acc.w);
    }

    const float inv = 1.0f / den;
    float4 o;
    o.x = acc.x * inv; o.y = acc.y * inv; o.z = acc.z * inv; o.w = acc.w * inv;
    ((float4*)out)[(size_t)b * F4 + lane] = o;
}

extern "C" void kernel_launch(void* const* d_in, const int* in_sizes, int n_in,
                              void* d_out, int out_size, void* d_ws, size_t ws_size,
                              hipStream_t stream)
{
    const int*   nodes = (const int*)d_in[0];
    const int*   nbr   = (const int*)d_in[1];
    const float* feats = (const float*)d_in[2];
    float*       out   = (float*)d_out;

    const int B = in_sizes[0];  // 10000

    const int grid = (B + RPB - 1) / RPB;
    aggregator_kernel<<<grid, 256, 0, stream>>>(nodes, nbr, feats, out, B);
}